// Round 1
// baseline (2829.654 us; speedup 1.0000x reference)
//
#include <hip/hip_runtime.h>

#define B_  128
#define N_  32
#define L_  36
#define DS  512
#define DV  1024
#define H_  512
#define P_  496
#define R_  63488      // B_*P_
#define K1  1536       // 3*DS

// ---------- wave helpers ----------
__device__ __forceinline__ float wave_sum(float v){
  #pragma unroll
  for (int m = 32; m >= 1; m >>= 1) v += __shfl_xor(v, m);
  return v;
}
__device__ __forceinline__ float wave_max(float v){
  #pragma unroll
  for (int m = 32; m >= 1; m >>= 1) v = fmaxf(v, __shfl_xor(v, m));
  return v;
}

// ---------- tiny setup kernels ----------
__global__ void init_pairs(int* iu, int* ju){
  int p = threadIdx.x;
  if (p < P_){
    int i = 0, rem = p, cnt = N_ - 1;
    while (rem >= cnt){ rem -= cnt; ++i; --cnt; }
    iu[p] = i; ju[p] = i + 1 + rem;
  }
}

__global__ void count_kernel(const float* __restrict__ sm, const float* __restrict__ im,
                             float* cnt_s, float* cnt_i){
  int t = threadIdx.x;  // 256
  if (t < B_){
    float s = 0.f;
    for (int n = 0; n < N_; ++n) s += sm[t*N_ + n];
    cnt_s[t] = s;
  } else {
    int j = t - B_;
    float s = 0.f;
    for (int l = 0; l < L_; ++l) s += im[j*L_ + l];
    cnt_i[j] = s;
  }
}

// ---------- SG = span @ Wg : (4096 x 1024, K=512) ----------
__global__ __launch_bounds__(256) void gemm_sg(const float* __restrict__ A,
                                               const float* __restrict__ Bm,
                                               float* __restrict__ C){
  __shared__ float sA[16][65];
  __shared__ float sB[16][65];
  const int t = threadIdx.x, tx = t & 15, ty = t >> 4;
  const int bm = blockIdx.y * 64, bn = blockIdx.x * 64;
  const int arow = t >> 2, akk = (t & 3) * 4;
  const int bkk = t >> 4, bcol = (t & 15) * 4;
  const float* Arow = A + (bm + arow) * DS;
  float acc[4][4] = {};
  for (int k0 = 0; k0 < DS; k0 += 16){
    float4 va = *(const float4*)(Arow + k0 + akk);
    sA[akk+0][arow] = va.x; sA[akk+1][arow] = va.y; sA[akk+2][arow] = va.z; sA[akk+3][arow] = va.w;
    float4 vb = *(const float4*)(Bm + (k0 + bkk) * DV + bn + bcol);
    sB[bkk][bcol+0] = vb.x; sB[bkk][bcol+1] = vb.y; sB[bkk][bcol+2] = vb.z; sB[bkk][bcol+3] = vb.w;
    __syncthreads();
    #pragma unroll
    for (int kk = 0; kk < 16; ++kk){
      float a[4], b[4];
      #pragma unroll
      for (int i = 0; i < 4; ++i) a[i] = sA[kk][ty*4 + i];
      #pragma unroll
      for (int j = 0; j < 4; ++j) b[j] = sB[kk][tx*4 + j];
      #pragma unroll
      for (int i = 0; i < 4; ++i)
        #pragma unroll
        for (int j = 0; j < 4; ++j) acc[i][j] = fmaf(a[i], b[j], acc[i][j]);
    }
    __syncthreads();
  }
  #pragma unroll
  for (int i = 0; i < 4; ++i){
    float* Cr = C + (bm + ty*4 + i) * DV + bn + tx*4;
    #pragma unroll
    for (int j = 0; j < 4; ++j) Cr[j] = acc[i][j];
  }
}

// ---------- M[b] = SG[b] (32x1024) @ img[b]^T (36x1024) ----------
__global__ __launch_bounds__(256) void batched_m(const float* __restrict__ SG,
                                                 const float* __restrict__ img,
                                                 float* __restrict__ Mout){
  const int b = blockIdx.x;
  __shared__ float sA[N_][129];
  __shared__ float sI[L_][129];
  const int t = threadIdx.x;
  int n_[5], l_[5];
  float acc[5] = {0.f,0.f,0.f,0.f,0.f};
  #pragma unroll
  for (int o = 0; o < 5; ++o){
    int out = t + 256*o;
    if (out < N_*L_){ n_[o] = out / L_; l_[o] = out % L_; } else { n_[o]=0; l_[o]=0; }
  }
  for (int k0 = 0; k0 < DV; k0 += 128){
    #pragma unroll
    for (int q = 0; q < 4; ++q){          // 32*128 = 4096 = 1024 float4
      int idx = t + 256*q;
      int row = idx >> 5;
      int k = (idx & 31) * 4;
      float4 v = *(const float4*)&SG[(b*N_ + row)*DV + k0 + k];
      sA[row][k] = v.x; sA[row][k+1] = v.y; sA[row][k+2] = v.z; sA[row][k+3] = v.w;
    }
    #pragma unroll
    for (int q = 0; q < 5; ++q){          // 36*128 = 4608 = 1152 float4
      int idx = t + 256*q;
      if (idx < 1152){
        int row = idx >> 5;
        int k = (idx & 31) * 4;
        float4 v = *(const float4*)&img[(b*L_ + row)*DV + k0 + k];
        sI[row][k] = v.x; sI[row][k+1] = v.y; sI[row][k+2] = v.z; sI[row][k+3] = v.w;
      }
    }
    __syncthreads();
    for (int kk = 0; kk < 128; ++kk){
      #pragma unroll
      for (int o = 0; o < 5; ++o){
        if (t + 256*o < N_*L_)
          acc[o] = fmaf(sA[n_[o]][kk], sI[l_[o]][kk], acc[o]);
      }
    }
    __syncthreads();
  }
  #pragma unroll
  for (int o = 0; o < 5; ++o){
    int out = t + 256*o;
    if (out < N_*L_) Mout[b*N_*L_ + out] = acc[o];
  }
}

// ---------- Msum[i,l] = sum_n M[i,n,l]*sm[i,n]; Mtot[i] = sum_nl M ----------
__global__ void msum_kernel(const float* __restrict__ M, const float* __restrict__ sm,
                            float* Msum, float* Mtot){
  const int i = blockIdx.x, t = threadIdx.x;  // 64 threads (1 wave)
  if (t < L_){
    float s = 0.f;
    for (int n = 0; n < N_; ++n) s += M[i*N_*L_ + n*L_ + t] * sm[i*N_ + n];
    Msum[i*L_ + t] = s;
  }
  float tot = 0.f;
  for (int idx = t; idx < N_*L_; idx += 64) tot += M[i*N_*L_ + idx];
  tot = wave_sum(tot);
  if (t == 0) Mtot[i] = tot;
}

// ---------- sent[i,j] ----------
__global__ void sent_kernel(const float* __restrict__ Msum, const float* __restrict__ im,
                            const float* __restrict__ cnt_s, const float* __restrict__ cnt_i,
                            const float* __restrict__ Mtot, float* __restrict__ sent){
  const int i = blockIdx.x, j = threadIdx.x;  // 128 threads
  float s = 0.f;
  for (int l = 0; l < L_; ++l) s += Msum[i*L_ + l] * im[j*L_ + l];
  const float d = cnt_s[i] * cnt_i[j];
  sent[i*B_ + j] = (d != 0.f) ? (s / d) : (Mtot[i] * (1.f/(float)(N_*L_)));
}

// ---------- per-row/col logsumexp + rowsum ----------
__global__ void lse_kernel(const float* __restrict__ sent, float* lse_r, float* lse_c, float* rsum){
  const int i = blockIdx.x, t = threadIdx.x;  // 128 threads = 2 waves
  const int wid = t >> 6, lane = t & 63;
  __shared__ float sh[2];
  const float vr = sent[i*B_ + t];
  const float vc = sent[t*B_ + i];

  float m = wave_max(vr);
  if (lane == 0) sh[wid] = m;
  __syncthreads();
  const float mr = fmaxf(sh[0], sh[1]);
  __syncthreads();
  float e = wave_sum(expf(vr - mr));
  if (lane == 0) sh[wid] = e;
  __syncthreads();
  const float ser = sh[0] + sh[1];
  __syncthreads();
  float rs = wave_sum(vr);
  if (lane == 0) sh[wid] = rs;
  __syncthreads();
  const float rst = sh[0] + sh[1];
  __syncthreads();
  float mc0 = wave_max(vc);
  if (lane == 0) sh[wid] = mc0;
  __syncthreads();
  const float mc = fmaxf(sh[0], sh[1]);
  __syncthreads();
  float ec = wave_sum(expf(vc - mc));
  if (lane == 0) sh[wid] = ec;
  __syncthreads();
  const float sec = sh[0] + sh[1];
  if (t == 0){
    lse_r[i] = mr + logf(ser);
    lse_c[i] = mc + logf(sec);
    rsum[i]  = rst;
  }
}

__global__ void loss_final(const float* __restrict__ lse_r, const float* __restrict__ lse_c,
                           const float* __restrict__ rsum, float* __restrict__ out){
  const int t = threadIdx.x;  // 128
  const int wid = t >> 6, lane = t & 63;
  __shared__ float sh[4];
  float a = lse_r[t] + lse_c[t];
  float c = rsum[t];
  float as = wave_sum(a);
  float cs = wave_sum(c);
  if (lane == 0){ sh[wid] = as; sh[2 + wid] = cs; }
  __syncthreads();
  if (t == 0){
    float A = sh[0] + sh[1], C = sh[2] + sh[3];
    out[0] = A - 2.f * C / (float)B_;
  }
}

// ---------- text path ----------
__global__ void text_init(float* __restrict__ text, const float* __restrict__ b3){
  int r = blockIdx.x * 256 + threadIdx.x;
  if (r < R_) text[r] = b3[0];
}

// h1 = relu(feat @ W1 + b1), feat gathered on the fly. (63488 x 512, K=1536)
__global__ __launch_bounds__(256) void gemm_feat(const float* __restrict__ span,
                                                 const float* __restrict__ W1,
                                                 const float* __restrict__ bias1,
                                                 const int* __restrict__ iu, const int* __restrict__ ju,
                                                 float* __restrict__ h1){
  __shared__ float sA[16][65];
  __shared__ float sB[16][65];
  const int t = threadIdx.x, tx = t & 15, ty = t >> 4;
  const int bm = blockIdx.y * 64, bn = blockIdx.x * 64;
  const int arow = t >> 2, akk = (t & 3) * 4;
  const int bkk = t >> 4, bcol = (t & 15) * 4;
  const int r = bm + arow;
  const int b = r / P_;
  const int p = r - b * P_;
  const float* si = span + (b * N_ + iu[p]) * DS;
  const float* sj = span + (b * N_ + ju[p]) * DS;
  float acc[4][4] = {};
  for (int k0 = 0; k0 < K1; k0 += 16){
    const int k = k0 + akk;
    float4 va;
    if (k < DS)            va = *(const float4*)(si + k);
    else if (k < 2*DS)     va = *(const float4*)(sj + k - DS);
    else {
      float4 x = *(const float4*)(si + k - 2*DS);
      float4 y = *(const float4*)(sj + k - 2*DS);
      va = make_float4(x.x*y.x, x.y*y.y, x.z*y.z, x.w*y.w);
    }
    sA[akk+0][arow] = va.x; sA[akk+1][arow] = va.y; sA[akk+2][arow] = va.z; sA[akk+3][arow] = va.w;
    float4 vb = *(const float4*)(W1 + (k0 + bkk) * H_ + bn + bcol);
    sB[bkk][bcol+0] = vb.x; sB[bkk][bcol+1] = vb.y; sB[bkk][bcol+2] = vb.z; sB[bkk][bcol+3] = vb.w;
    __syncthreads();
    #pragma unroll
    for (int kk = 0; kk < 16; ++kk){
      float a[4], bb[4];
      #pragma unroll
      for (int i = 0; i < 4; ++i) a[i] = sA[kk][ty*4 + i];
      #pragma unroll
      for (int j = 0; j < 4; ++j) bb[j] = sB[kk][tx*4 + j];
      #pragma unroll
      for (int i = 0; i < 4; ++i)
        #pragma unroll
        for (int j = 0; j < 4; ++j) acc[i][j] = fmaf(a[i], bb[j], acc[i][j]);
    }
    __syncthreads();
  }
  #pragma unroll
  for (int i = 0; i < 4; ++i){
    float* Hr = h1 + (bm + ty*4 + i) * H_ + bn + tx*4;
    #pragma unroll
    for (int j = 0; j < 4; ++j) Hr[j] = fmaxf(acc[i][j] + bias1[bn + tx*4 + j], 0.f);
  }
}

// h2 = relu(h1 @ W2 + b2); text[r] += sum_h h2[r,h]*W3[h]  (fused, atomic partial sums)
__global__ __launch_bounds__(256) void gemm_h2(const float* __restrict__ h1,
                                               const float* __restrict__ W2,
                                               const float* __restrict__ bias2,
                                               const float* __restrict__ W3,
                                               float* __restrict__ text){
  __shared__ float sA[16][65];
  __shared__ float sB[16][65];
  const int t = threadIdx.x, tx = t & 15, ty = t >> 4;
  const int bm = blockIdx.y * 64, bn = blockIdx.x * 64;
  const int arow = t >> 2, akk = (t & 3) * 4;
  const int bkk = t >> 4, bcol = (t & 15) * 4;
  const float* Arow = h1 + (bm + arow) * H_;
  float acc[4][4] = {};
  for (int k0 = 0; k0 < H_; k0 += 16){
    float4 va = *(const float4*)(Arow + k0 + akk);
    sA[akk+0][arow] = va.x; sA[akk+1][arow] = va.y; sA[akk+2][arow] = va.z; sA[akk+3][arow] = va.w;
    float4 vb = *(const float4*)(W2 + (k0 + bkk) * H_ + bn + bcol);
    sB[bkk][bcol+0] = vb.x; sB[bkk][bcol+1] = vb.y; sB[bkk][bcol+2] = vb.z; sB[bkk][bcol+3] = vb.w;
    __syncthreads();
    #pragma unroll
    for (int kk = 0; kk < 16; ++kk){
      float a[4], bb[4];
      #pragma unroll
      for (int i = 0; i < 4; ++i) a[i] = sA[kk][ty*4 + i];
      #pragma unroll
      for (int j = 0; j < 4; ++j) bb[j] = sB[kk][tx*4 + j];
      #pragma unroll
      for (int i = 0; i < 4; ++i)
        #pragma unroll
        for (int j = 0; j < 4; ++j) acc[i][j] = fmaf(a[i], bb[j], acc[i][j]);
    }
    __syncthreads();
  }
  float w3v[4], b2v[4];
  #pragma unroll
  for (int j = 0; j < 4; ++j){ w3v[j] = W3[bn + tx*4 + j]; b2v[j] = bias2[bn + tx*4 + j]; }
  #pragma unroll
  for (int i = 0; i < 4; ++i){
    float s = 0.f;
    #pragma unroll
    for (int j = 0; j < 4; ++j){
      float c = fmaxf(acc[i][j] + b2v[j], 0.f);
      s = fmaf(c, w3v[j], s);
    }
    s += __shfl_xor(s, 1); s += __shfl_xor(s, 2); s += __shfl_xor(s, 4); s += __shfl_xor(s, 8);
    if (tx == 0) atomicAdd(&text[bm + ty*4 + i], s);
  }
}

extern "C" void kernel_launch(void* const* d_in, const int* in_sizes, int n_in,
                              void* d_out, int out_size, void* d_ws, size_t ws_size,
                              hipStream_t stream) {
  const float* span = (const float*)d_in[0];
  const float* img  = (const float*)d_in[1];
  const float* sm   = (const float*)d_in[2];
  const float* im   = (const float*)d_in[3];
  const float* Wg   = (const float*)d_in[4];
  const float* W1   = (const float*)d_in[5];
  const float* b1   = (const float*)d_in[6];
  const float* W2   = (const float*)d_in[7];
  const float* b2   = (const float*)d_in[8];
  const float* W3   = (const float*)d_in[9];
  const float* b3   = (const float*)d_in[10];

  float* out  = (float*)d_out;
  float* loss = out;
  float* Mout = out + 1;
  float* text = out + 1 + B_*N_*L_;

  float* ws   = (float*)d_ws;
  float* SG    = ws;                      // 4096*1024
  float* h1    = SG + 4096*1024;          // 63488*512
  float* Msum  = h1 + (size_t)R_*H_;      // 4608
  float* Mtot  = Msum + B_*L_;            // 128
  float* cnt_s = Mtot + B_;               // 128
  float* cnt_i = cnt_s + B_;              // 128
  float* sent  = cnt_i + B_;              // 16384
  float* lse_r = sent + B_*B_;            // 128
  float* lse_c = lse_r + B_;              // 128
  float* rsum  = lse_c + B_;              // 128
  int*   iu    = (int*)(rsum + B_);       // 496
  int*   ju    = iu + P_;                 // 496

  init_pairs<<<1, 512, 0, stream>>>(iu, ju);
  count_kernel<<<1, 256, 0, stream>>>(sm, im, cnt_s, cnt_i);
  gemm_sg<<<dim3(DV/64, 4096/64), 256, 0, stream>>>(span, Wg, SG);
  batched_m<<<B_, 256, 0, stream>>>(SG, img, Mout);
  msum_kernel<<<B_, 64, 0, stream>>>(Mout, sm, Msum, Mtot);
  sent_kernel<<<B_, B_, 0, stream>>>(Msum, im, cnt_s, cnt_i, Mtot, sent);
  lse_kernel<<<B_, B_, 0, stream>>>(sent, lse_r, lse_c, rsum);
  loss_final<<<1, B_, 0, stream>>>(lse_r, lse_c, rsum, loss);
  text_init<<<R_/256, 256, 0, stream>>>(text, b3);
  gemm_feat<<<dim3(H_/64, R_/64), 256, 0, stream>>>(span, W1, b1, iu, ju, h1);
  gemm_h2<<<dim3(H_/64, R_/64), 256, 0, stream>>>(h1, W2, b2, W3, text);
}

// Round 2
// 592.729 us; speedup vs baseline: 4.7739x; 4.7739x over previous
//
#include <hip/hip_runtime.h>

#define B_  128
#define N_  32
#define L_  36
#define DS  512
#define DV  1024
#define H_  512
#define P_  496
#define R_  63488      // B_*P_

typedef __attribute__((ext_vector_type(8))) short bf16x8;
typedef __attribute__((ext_vector_type(4))) float f32x4;

__device__ __forceinline__ ushort f2bf(float x){
  unsigned u = __builtin_bit_cast(unsigned, x);
  return (ushort)((u + 0x7FFFu + ((u >> 16) & 1u)) >> 16);
}

__device__ __forceinline__ void gload16(const void* g, void* l){
  __builtin_amdgcn_global_load_lds((const __attribute__((address_space(1))) unsigned*)g,
                                   (__attribute__((address_space(3))) unsigned*)l, 16, 0, 0);
}

// ---------- wave helpers ----------
__device__ __forceinline__ float wave_sum(float v){
  #pragma unroll
  for (int m = 32; m >= 1; m >>= 1) v += __shfl_xor(v, m);
  return v;
}
__device__ __forceinline__ float wave_max(float v){
  #pragma unroll
  for (int m = 32; m >= 1; m >>= 1) v = fmaxf(v, __shfl_xor(v, m));
  return v;
}

// ---------- tiny setup kernels ----------
__global__ void init_pairs(int* iu, int* ju){
  int p = threadIdx.x;
  if (p < P_){
    int i = 0, rem = p, cnt = N_ - 1;
    while (rem >= cnt){ rem -= cnt; ++i; --cnt; }
    iu[p] = i; ju[p] = i + 1 + rem;
  }
}

__global__ void count_kernel(const float* __restrict__ sm, const float* __restrict__ im,
                             float* cnt_s, float* cnt_i){
  int t = threadIdx.x;  // 256
  if (t < B_){
    float s = 0.f;
    for (int n = 0; n < N_; ++n) s += sm[t*N_ + n];
    cnt_s[t] = s;
  } else {
    int j = t - B_;
    float s = 0.f;
    for (int l = 0; l < L_; ++l) s += im[j*L_ + l];
    cnt_i[j] = s;
  }
}

// ---------- conversions for bf16 path ----------
// span fp32 -> span_bf (4096x512)
__global__ void conv_span(const float* __restrict__ span, ushort* __restrict__ sb){
  int idx = blockIdx.x * 256 + threadIdx.x;   // 4 elems each; 2M total
  float4 v = *(const float4*)&span[idx * 4];
  ushort4 o; o.x = f2bf(v.x); o.y = f2bf(v.y); o.z = f2bf(v.z); o.w = f2bf(v.w);
  *(ushort4*)&sb[idx * 4] = o;
}

// 512x512 fp32 tile transpose -> bf16: dst[n][k] = src[k*512+n]
__global__ void transpose512(const float* __restrict__ src, ushort* __restrict__ dst){
  __shared__ float tile[32][33];
  int n0 = blockIdx.x * 32, k0 = blockIdx.y * 32;
  int x = threadIdx.x, y = threadIdx.y;   // 32 x 8
  #pragma unroll
  for (int i = 0; i < 4; ++i) tile[y + 8*i][x] = src[(k0 + y + 8*i) * 512 + n0 + x];
  __syncthreads();
  #pragma unroll
  for (int i = 0; i < 4; ++i) dst[(n0 + y + 8*i) * 512 + k0 + x] = f2bf(tile[x][y + 8*i]);
}

// Z[r][k] = span[b,i,k] * span[b,j,k], bf16
__global__ void make_z(const float* __restrict__ span, const int* __restrict__ iu,
                       const int* __restrict__ ju, ushort* __restrict__ Z){
  int idx = blockIdx.x * 256 + threadIdx.x;    // 4 elems each; R_*512/4 total
  int r = idx >> 7;
  int k = (idx & 127) << 2;
  int b = r / P_, p = r - b * P_;
  float4 x = *(const float4*)&span[(b * N_ + iu[p]) * DS + k];
  float4 y = *(const float4*)&span[(b * N_ + ju[p]) * DS + k];
  ushort4 o;
  o.x = f2bf(x.x * y.x); o.y = f2bf(x.y * y.y); o.z = f2bf(x.z * y.z); o.w = f2bf(x.w * y.w);
  *(ushort4*)&Z[(size_t)r * 512 + k] = o;
}

// ---------- shared bf16 MFMA mainloop: 128x128 tile, K=512, BK=32 ----------
// A: [M][512] bf16 packed; BT: [N][512] bf16 packed. acc[i][j] = 16x16 D tile.
__device__ __forceinline__ void mma_mainloop(const ushort* __restrict__ A,
                                             const ushort* __restrict__ BT,
                                             size_t m0, int n0,
                                             ushort* sA, ushort* sB, f32x4 acc[4][4]){
  const int tid = threadIdx.x, wid = tid >> 6, lane = tid & 63;
  const int wm = (wid >> 1) * 64, wn = (wid & 1) * 64;
  const int quad = lane >> 4, fm = lane & 15;
  const char* gA = (const char*)A + (m0 + (size_t)(wid * 32 + (lane >> 2))) * 1024 + (lane & 3) * 16;
  const char* gB = (const char*)BT + ((size_t)n0 + wid * 32 + (lane >> 2)) * 1024 + (lane & 3) * 16;
  ushort* lA = sA + wid * 32 * 32;
  ushort* lB = sB + wid * 32 * 32;
  #pragma unroll 1
  for (int ks = 0; ks < 16; ++ks){
    gload16(gA,             lA);
    gload16(gA + 16 * 1024, lA + 16 * 32);
    gload16(gB,             lB);
    gload16(gB + 16 * 1024, lB + 16 * 32);
    __syncthreads();
    bf16x8 af[4], bg[4];
    #pragma unroll
    for (int i = 0; i < 4; ++i){
      af[i] = *(const bf16x8*)&sA[(wm + i * 16 + fm) * 32 + quad * 8];
      bg[i] = *(const bf16x8*)&sB[(wn + i * 16 + fm) * 32 + quad * 8];
    }
    #pragma unroll
    for (int i = 0; i < 4; ++i)
      #pragma unroll
      for (int j = 0; j < 4; ++j)
        acc[i][j] = __builtin_amdgcn_mfma_f32_16x16x32_bf16(af[i], bg[j], acc[i][j], 0, 0, 0);
    __syncthreads();
    gA += 64; gB += 64;
  }
}

// UV = span_bf @ [W1a|W1b]  (4096 x 1024), fp32 out
__global__ __launch_bounds__(256) void gemm_uv(const ushort* __restrict__ A,
                                               const ushort* __restrict__ BT,
                                               float* __restrict__ C){
  __shared__ ushort sA[4096], sB[4096];
  f32x4 acc[4][4] = {};
  size_t m0 = (size_t)blockIdx.y * 128; int n0 = blockIdx.x * 128;
  mma_mainloop(A, BT, m0, n0, sA, sB, acc);
  const int tid = threadIdx.x, wid = tid >> 6, lane = tid & 63;
  const int wm = (wid >> 1) * 64, wn = (wid & 1) * 64, quad = lane >> 4, fm = lane & 15;
  #pragma unroll
  for (int i = 0; i < 4; ++i)
    #pragma unroll
    for (int r = 0; r < 4; ++r){
      size_t row = m0 + wm + i * 16 + quad * 4 + r;
      #pragma unroll
      for (int j = 0; j < 4; ++j){
        int col = n0 + wn + j * 16 + fm;
        C[row * 1024 + col] = acc[i][j][r];
      }
    }
}

// h1 = relu(Z@W1c + U[b,i] + V[b,j] + b1), bf16 out (63488 x 512)
__global__ __launch_bounds__(256) void gemm_z(const ushort* __restrict__ A,
                                              const ushort* __restrict__ BT,
                                              const float* __restrict__ UV,
                                              const float* __restrict__ b1,
                                              const int* __restrict__ iu, const int* __restrict__ ju,
                                              ushort* __restrict__ h1){
  __shared__ ushort sA[4096], sB[4096];
  f32x4 acc[4][4] = {};
  size_t m0 = (size_t)blockIdx.y * 128; int n0 = blockIdx.x * 128;
  mma_mainloop(A, BT, m0, n0, sA, sB, acc);
  const int tid = threadIdx.x, wid = tid >> 6, lane = tid & 63;
  const int wm = (wid >> 1) * 64, wn = (wid & 1) * 64, quad = lane >> 4, fm = lane & 15;
  #pragma unroll
  for (int i = 0; i < 4; ++i)
    #pragma unroll
    for (int r = 0; r < 4; ++r){
      int row = (int)m0 + wm + i * 16 + quad * 4 + r;
      int b = row / P_, p = row - b * P_;
      const float* Ur = UV + (size_t)(b * N_ + iu[p]) * 1024;
      const float* Vr = UV + (size_t)(b * N_ + ju[p]) * 1024 + 512;
      #pragma unroll
      for (int j = 0; j < 4; ++j){
        int col = n0 + wn + j * 16 + fm;
        float h = acc[i][j][r] + Ur[col] + Vr[col] + b1[col];
        h1[(size_t)row * 512 + col] = f2bf(fmaxf(h, 0.f));
      }
    }
}

// text += sum_col relu(h1@W2 + b2) * W3
__global__ __launch_bounds__(256) void gemm_h2(const ushort* __restrict__ A,
                                               const ushort* __restrict__ BT,
                                               const float* __restrict__ b2,
                                               const float* __restrict__ W3,
                                               float* __restrict__ text){
  __shared__ ushort sA[4096], sB[4096];
  f32x4 acc[4][4] = {};
  size_t m0 = (size_t)blockIdx.y * 128; int n0 = blockIdx.x * 128;
  mma_mainloop(A, BT, m0, n0, sA, sB, acc);
  const int tid = threadIdx.x, wid = tid >> 6, lane = tid & 63;
  const int wm = (wid >> 1) * 64, wn = (wid & 1) * 64, quad = lane >> 4, fm = lane & 15;
  #pragma unroll
  for (int i = 0; i < 4; ++i)
    #pragma unroll
    for (int r = 0; r < 4; ++r){
      int row = (int)m0 + wm + i * 16 + quad * 4 + r;
      float s = 0.f;
      #pragma unroll
      for (int j = 0; j < 4; ++j){
        int col = n0 + wn + j * 16 + fm;
        float h = fmaxf(acc[i][j][r] + b2[col], 0.f);
        s = fmaf(h, W3[col], s);
      }
      s += __shfl_xor(s, 1); s += __shfl_xor(s, 2); s += __shfl_xor(s, 4); s += __shfl_xor(s, 8);
      if (fm == 0) atomicAdd(&text[row], s);
    }
}

// ---------- fp32 M path (unchanged) ----------
__global__ __launch_bounds__(256) void gemm_sg(const float* __restrict__ A,
                                               const float* __restrict__ Bm,
                                               float* __restrict__ C){
  __shared__ float sA[16][65];
  __shared__ float sB[16][65];
  const int t = threadIdx.x, tx = t & 15, ty = t >> 4;
  const int bm = blockIdx.y * 64, bn = blockIdx.x * 64;
  const int arow = t >> 2, akk = (t & 3) * 4;
  const int bkk = t >> 4, bcol = (t & 15) * 4;
  const float* Arow = A + (bm + arow) * DS;
  float acc[4][4] = {};
  for (int k0 = 0; k0 < DS; k0 += 16){
    float4 va = *(const float4*)(Arow + k0 + akk);
    sA[akk+0][arow] = va.x; sA[akk+1][arow] = va.y; sA[akk+2][arow] = va.z; sA[akk+3][arow] = va.w;
    float4 vb = *(const float4*)(Bm + (k0 + bkk) * DV + bn + bcol);
    sB[bkk][bcol+0] = vb.x; sB[bkk][bcol+1] = vb.y; sB[bkk][bcol+2] = vb.z; sB[bkk][bcol+3] = vb.w;
    __syncthreads();
    #pragma unroll
    for (int kk = 0; kk < 16; ++kk){
      float a[4], b[4];
      #pragma unroll
      for (int i = 0; i < 4; ++i) a[i] = sA[kk][ty*4 + i];
      #pragma unroll
      for (int j = 0; j < 4; ++j) b[j] = sB[kk][tx*4 + j];
      #pragma unroll
      for (int i = 0; i < 4; ++i)
        #pragma unroll
        for (int j = 0; j < 4; ++j) acc[i][j] = fmaf(a[i], b[j], acc[i][j]);
    }
    __syncthreads();
  }
  #pragma unroll
  for (int i = 0; i < 4; ++i){
    float* Cr = C + (bm + ty*4 + i) * DV + bn + tx*4;
    #pragma unroll
    for (int j = 0; j < 4; ++j) Cr[j] = acc[i][j];
  }
}

__global__ __launch_bounds__(256) void batched_m(const float* __restrict__ SG,
                                                 const float* __restrict__ img,
                                                 float* __restrict__ Mout){
  const int b = blockIdx.x;
  __shared__ float sA[N_][129];
  __shared__ float sI[L_][129];
  const int t = threadIdx.x;
  int n_[5], l_[5];
  float acc[5] = {0.f,0.f,0.f,0.f,0.f};
  #pragma unroll
  for (int o = 0; o < 5; ++o){
    int out = t + 256*o;
    if (out < N_*L_){ n_[o] = out / L_; l_[o] = out % L_; } else { n_[o]=0; l_[o]=0; }
  }
  for (int k0 = 0; k0 < DV; k0 += 128){
    #pragma unroll
    for (int q = 0; q < 4; ++q){
      int idx = t + 256*q;
      int row = idx >> 5;
      int k = (idx & 31) * 4;
      float4 v = *(const float4*)&SG[(b*N_ + row)*DV + k0 + k];
      sA[row][k] = v.x; sA[row][k+1] = v.y; sA[row][k+2] = v.z; sA[row][k+3] = v.w;
    }
    #pragma unroll
    for (int q = 0; q < 5; ++q){
      int idx = t + 256*q;
      if (idx < 1152){
        int row = idx >> 5;
        int k = (idx & 31) * 4;
        float4 v = *(const float4*)&img[(b*L_ + row)*DV + k0 + k];
        sI[row][k] = v.x; sI[row][k+1] = v.y; sI[row][k+2] = v.z; sI[row][k+3] = v.w;
      }
    }
    __syncthreads();
    for (int kk = 0; kk < 128; ++kk){
      #pragma unroll
      for (int o = 0; o < 5; ++o){
        if (t + 256*o < N_*L_)
          acc[o] = fmaf(sA[n_[o]][kk], sI[l_[o]][kk], acc[o]);
      }
    }
    __syncthreads();
  }
  #pragma unroll
  for (int o = 0; o < 5; ++o){
    int out = t + 256*o;
    if (out < N_*L_) Mout[b*N_*L_ + out] = acc[o];
  }
}

__global__ void msum_kernel(const float* __restrict__ M, const float* __restrict__ sm,
                            float* Msum, float* Mtot){
  const int i = blockIdx.x, t = threadIdx.x;  // 64 threads
  if (t < L_){
    float s = 0.f;
    for (int n = 0; n < N_; ++n) s += M[i*N_*L_ + n*L_ + t] * sm[i*N_ + n];
    Msum[i*L_ + t] = s;
  }
  float tot = 0.f;
  for (int idx = t; idx < N_*L_; idx += 64) tot += M[i*N_*L_ + idx];
  tot = wave_sum(tot);
  if (t == 0) Mtot[i] = tot;
}

__global__ void sent_kernel(const float* __restrict__ Msum, const float* __restrict__ im,
                            const float* __restrict__ cnt_s, const float* __restrict__ cnt_i,
                            const float* __restrict__ Mtot, float* __restrict__ sent){
  const int i = blockIdx.x, j = threadIdx.x;  // 128 threads
  float s = 0.f;
  for (int l = 0; l < L_; ++l) s += Msum[i*L_ + l] * im[j*L_ + l];
  const float d = cnt_s[i] * cnt_i[j];
  sent[i*B_ + j] = (d != 0.f) ? (s / d) : (Mtot[i] * (1.f/(float)(N_*L_)));
}

__global__ void lse_kernel(const float* __restrict__ sent, float* lse_r, float* lse_c, float* rsum){
  const int i = blockIdx.x, t = threadIdx.x;  // 128 threads = 2 waves
  const int wid = t >> 6, lane = t & 63;
  __shared__ float sh[2];
  const float vr = sent[i*B_ + t];
  const float vc = sent[t*B_ + i];

  float m = wave_max(vr);
  if (lane == 0) sh[wid] = m;
  __syncthreads();
  const float mr = fmaxf(sh[0], sh[1]);
  __syncthreads();
  float e = wave_sum(expf(vr - mr));
  if (lane == 0) sh[wid] = e;
  __syncthreads();
  const float ser = sh[0] + sh[1];
  __syncthreads();
  float rs = wave_sum(vr);
  if (lane == 0) sh[wid] = rs;
  __syncthreads();
  const float rst = sh[0] + sh[1];
  __syncthreads();
  float mc0 = wave_max(vc);
  if (lane == 0) sh[wid] = mc0;
  __syncthreads();
  const float mc = fmaxf(sh[0], sh[1]);
  __syncthreads();
  float ec = wave_sum(expf(vc - mc));
  if (lane == 0) sh[wid] = ec;
  __syncthreads();
  const float sec = sh[0] + sh[1];
  if (t == 0){
    lse_r[i] = mr + logf(ser);
    lse_c[i] = mc + logf(sec);
    rsum[i]  = rst;
  }
}

__global__ void loss_final(const float* __restrict__ lse_r, const float* __restrict__ lse_c,
                           const float* __restrict__ rsum, float* __restrict__ out){
  const int t = threadIdx.x;  // 128
  const int wid = t >> 6, lane = t & 63;
  __shared__ float sh[4];
  float a = lse_r[t] + lse_c[t];
  float c = rsum[t];
  float as = wave_sum(a);
  float cs = wave_sum(c);
  if (lane == 0){ sh[wid] = as; sh[2 + wid] = cs; }
  __syncthreads();
  if (t == 0){
    float A = sh[0] + sh[1], C = sh[2] + sh[3];
    out[0] = A - 2.f * C / (float)B_;
  }
}

__global__ void text_init(float* __restrict__ text, const float* __restrict__ b3){
  int r = blockIdx.x * 256 + threadIdx.x;
  if (r < R_) text[r] = b3[0];
}

extern "C" void kernel_launch(void* const* d_in, const int* in_sizes, int n_in,
                              void* d_out, int out_size, void* d_ws, size_t ws_size,
                              hipStream_t stream) {
  const float* span = (const float*)d_in[0];
  const float* img  = (const float*)d_in[1];
  const float* sm   = (const float*)d_in[2];
  const float* im   = (const float*)d_in[3];
  const float* Wg   = (const float*)d_in[4];
  const float* W1   = (const float*)d_in[5];
  const float* b1   = (const float*)d_in[6];
  const float* W2   = (const float*)d_in[7];
  const float* b2   = (const float*)d_in[8];
  const float* W3   = (const float*)d_in[9];
  const float* b3   = (const float*)d_in[10];

  float* out  = (float*)d_out;
  float* loss = out;
  float* Mout = out + 1;
  float* text = out + 1 + B_*N_*L_;

  float* ws   = (float*)d_ws;
  float* SG    = ws;                         // 4096*1024 fp32
  float* UV    = SG + 4096*1024;             // 4096*1024 fp32
  ushort* h1bf = (ushort*)(UV + 4096*1024);  // R_*512 bf16
  ushort* Zbf  = h1bf + (size_t)R_*512;      // R_*512 bf16
  ushort* spbf = Zbf + (size_t)R_*512;       // 4096*512 bf16
  ushort* UVBT = spbf + 4096*512;            // 1024*512 bf16
  ushort* W1cT = UVBT + 1024*512;            // 512*512 bf16
  ushort* W2T  = W1cT + 512*512;             // 512*512 bf16
  float* Msum  = (float*)(W2T + 512*512);    // 4608
  float* Mtot  = Msum + B_*L_;
  float* cnt_s = Mtot + B_;
  float* cnt_i = cnt_s + B_;
  float* sent  = cnt_i + B_;                 // 16384
  float* lse_r = sent + B_*B_;
  float* lse_c = lse_r + B_;
  float* rsum  = lse_c + B_;
  int*   iu    = (int*)(rsum + B_);          // 496
  int*   ju    = iu + P_;                    // 496

  init_pairs<<<1, 512, 0, stream>>>(iu, ju);
  count_kernel<<<1, 256, 0, stream>>>(sm, im, cnt_s, cnt_i);

  // bf16 prep
  conv_span<<<2048, 256, 0, stream>>>(span, spbf);
  transpose512<<<dim3(16,16), dim3(32,8), 0, stream>>>(W1,            UVBT);
  transpose512<<<dim3(16,16), dim3(32,8), 0, stream>>>(W1 + 512*512,  UVBT + 512*512);
  transpose512<<<dim3(16,16), dim3(32,8), 0, stream>>>(W1 + 1024*512, W1cT);
  transpose512<<<dim3(16,16), dim3(32,8), 0, stream>>>(W2,            W2T);
  make_z<<<R_*512/4/256, 256, 0, stream>>>(span, iu, ju, Zbf);

  // M path (fp32)
  gemm_sg<<<dim3(DV/64, 4096/64), 256, 0, stream>>>(span, Wg, SG);
  batched_m<<<B_, 256, 0, stream>>>(SG, img, Mout);
  msum_kernel<<<B_, 64, 0, stream>>>(Mout, sm, Msum, Mtot);
  sent_kernel<<<B_, B_, 0, stream>>>(Msum, im, cnt_s, cnt_i, Mtot, sent);
  lse_kernel<<<B_, B_, 0, stream>>>(sent, lse_r, lse_c, rsum);
  loss_final<<<1, B_, 0, stream>>>(lse_r, lse_c, rsum, loss);

  // text path (bf16 MFMA)
  gemm_uv<<<dim3(8, 32),  256, 0, stream>>>(spbf, UVBT, UV);
  gemm_z <<<dim3(4, 496), 256, 0, stream>>>(Zbf, W1cT, UV, b1, iu, ju, h1bf);
  text_init<<<R_/256, 256, 0, stream>>>(text, b3);
  gemm_h2<<<dim3(4, 496), 256, 0, stream>>>(h1bf, W2T, b2, W3, text);
}

// Round 3
// 322.894 us; speedup vs baseline: 8.7634x; 1.8357x over previous
//
#include <hip/hip_runtime.h>

#define B_  128
#define N_  32
#define L_  36
#define DS  512
#define DV  1024
#define H_  512
#define P_  496
#define R_  63488      // B_*P_

typedef __attribute__((ext_vector_type(8))) short bf16x8;
typedef __attribute__((ext_vector_type(4))) float f32x4;

__device__ __forceinline__ ushort f2bf(float x){
  unsigned u = __builtin_bit_cast(unsigned, x);
  return (ushort)((u + 0x7FFFu + ((u >> 16) & 1u)) >> 16);
}
__device__ __forceinline__ float bf2f(ushort u){
  unsigned v = ((unsigned)u) << 16;
  return __builtin_bit_cast(float, v);
}

__device__ __forceinline__ void gload16(const void* g, void* l){
  __builtin_amdgcn_global_load_lds((const __attribute__((address_space(1))) unsigned*)g,
                                   (__attribute__((address_space(3))) unsigned*)l, 16, 0, 0);
}

// ---------- wave helpers ----------
__device__ __forceinline__ float wave_sum(float v){
  #pragma unroll
  for (int m = 32; m >= 1; m >>= 1) v += __shfl_xor(v, m);
  return v;
}
__device__ __forceinline__ float wave_max(float v){
  #pragma unroll
  for (int m = 32; m >= 1; m >>= 1) v = fmaxf(v, __shfl_xor(v, m));
  return v;
}

// ---------- tiny setup kernels ----------
__global__ void init_pairs(int* iu, int* ju){
  int p = threadIdx.x;
  if (p < P_){
    int i = 0, rem = p, cnt = N_ - 1;
    while (rem >= cnt){ rem -= cnt; ++i; --cnt; }
    iu[p] = i; ju[p] = i + 1 + rem;
  }
}

__global__ void count_kernel(const float* __restrict__ sm, const float* __restrict__ im,
                             float* cnt_s, float* cnt_i){
  int t = threadIdx.x;  // 256
  if (t < B_){
    float s = 0.f;
    for (int n = 0; n < N_; ++n) s += sm[t*N_ + n];
    cnt_s[t] = s;
  } else {
    int j = t - B_;
    float s = 0.f;
    for (int l = 0; l < L_; ++l) s += im[j*L_ + l];
    cnt_i[j] = s;
  }
}

// ---------- conversions ----------
__global__ void conv_f2bf(const float* __restrict__ src, ushort* __restrict__ dst){
  int idx = blockIdx.x * 256 + threadIdx.x;   // 4 elems each
  float4 v = *(const float4*)&src[idx * 4];
  ushort4 o; o.x = f2bf(v.x); o.y = f2bf(v.y); o.z = f2bf(v.z); o.w = f2bf(v.w);
  *(ushort4*)&dst[idx * 4] = o;
}

// src: K x N fp32 -> dst: N x K bf16
__global__ void transpose_bf(const float* __restrict__ src, ushort* __restrict__ dst,
                             int K, int N){
  __shared__ float tile[32][33];
  int n0 = blockIdx.x * 32, k0 = blockIdx.y * 32;
  int x = threadIdx.x, y = threadIdx.y;   // 32 x 8
  #pragma unroll
  for (int i = 0; i < 4; ++i) tile[y + 8*i][x] = src[(k0 + y + 8*i) * N + n0 + x];
  __syncthreads();
  #pragma unroll
  for (int i = 0; i < 4; ++i) dst[(n0 + y + 8*i) * K + k0 + x] = f2bf(tile[x][y + 8*i]);
}

// Z[r][k] = span[b,i,k] * span[b,j,k], bf16
__global__ void make_z(const float* __restrict__ span, const int* __restrict__ iu,
                       const int* __restrict__ ju, ushort* __restrict__ Z){
  int idx = blockIdx.x * 256 + threadIdx.x;    // 4 elems each
  int r = idx >> 7;
  int k = (idx & 127) << 2;
  int b = r / P_, p = r - b * P_;
  float4 x = *(const float4*)&span[(b * N_ + iu[p]) * DS + k];
  float4 y = *(const float4*)&span[(b * N_ + ju[p]) * DS + k];
  ushort4 o;
  o.x = f2bf(x.x * y.x); o.y = f2bf(x.y * y.y); o.z = f2bf(x.z * y.z); o.w = f2bf(x.w * y.w);
  *(ushort4*)&Z[(size_t)r * 512 + k] = o;
}

// ---------- shared bf16 MFMA mainloop: 128x128 tile, K=512, BK=32 ----------
__device__ __forceinline__ void mma_mainloop(const ushort* __restrict__ A,
                                             const ushort* __restrict__ BT,
                                             size_t m0, int n0,
                                             ushort* sA, ushort* sB, f32x4 acc[4][4]){
  const int tid = threadIdx.x, wid = tid >> 6, lane = tid & 63;
  const int wm = (wid >> 1) * 64, wn = (wid & 1) * 64;
  const int quad = lane >> 4, fm = lane & 15;
  const char* gA = (const char*)A + (m0 + (size_t)(wid * 32 + (lane >> 2))) * 1024 + (lane & 3) * 16;
  const char* gB = (const char*)BT + ((size_t)n0 + wid * 32 + (lane >> 2)) * 1024 + (lane & 3) * 16;
  ushort* lA = sA + wid * 32 * 32;
  ushort* lB = sB + wid * 32 * 32;
  #pragma unroll 1
  for (int ks = 0; ks < 16; ++ks){
    gload16(gA,             lA);
    gload16(gA + 16 * 1024, lA + 16 * 32);
    gload16(gB,             lB);
    gload16(gB + 16 * 1024, lB + 16 * 32);
    __syncthreads();
    bf16x8 af[4], bg[4];
    #pragma unroll
    for (int i = 0; i < 4; ++i){
      af[i] = *(const bf16x8*)&sA[(wm + i * 16 + fm) * 32 + quad * 8];
      bg[i] = *(const bf16x8*)&sB[(wn + i * 16 + fm) * 32 + quad * 8];
    }
    #pragma unroll
    for (int i = 0; i < 4; ++i)
      #pragma unroll
      for (int j = 0; j < 4; ++j)
        acc[i][j] = __builtin_amdgcn_mfma_f32_16x16x32_bf16(af[i], bg[j], acc[i][j], 0, 0, 0);
    __syncthreads();
    gA += 64; gB += 64;
  }
}

// UV = span_bf @ [W1a|W1b]  (4096 x 1024), bf16 out
__global__ __launch_bounds__(256) void gemm_uv(const ushort* __restrict__ A,
                                               const ushort* __restrict__ BT,
                                               ushort* __restrict__ C){
  __shared__ ushort sA[4096], sB[4096];
  f32x4 acc[4][4] = {};
  size_t m0 = (size_t)blockIdx.y * 128; int n0 = blockIdx.x * 128;
  mma_mainloop(A, BT, m0, n0, sA, sB, acc);
  const int tid = threadIdx.x, wid = tid >> 6, lane = tid & 63;
  const int wm = (wid >> 1) * 64, wn = (wid & 1) * 64, quad = lane >> 4, fm = lane & 15;
  #pragma unroll
  for (int i = 0; i < 4; ++i)
    #pragma unroll
    for (int r = 0; r < 4; ++r){
      size_t row = m0 + wm + i * 16 + quad * 4 + r;
      #pragma unroll
      for (int j = 0; j < 4; ++j){
        int col = n0 + wn + j * 16 + fm;
        C[row * 1024 + col] = f2bf(acc[i][j][r]);
      }
    }
}

// SGbf = span_bf @ Wg^T-layout  (4096 x 1024), bf16 out
__global__ __launch_bounds__(256) void gemm_sgbf(const ushort* __restrict__ A,
                                                 const ushort* __restrict__ BT,
                                                 ushort* __restrict__ C){
  __shared__ ushort sA[4096], sB[4096];
  f32x4 acc[4][4] = {};
  size_t m0 = (size_t)blockIdx.y * 128; int n0 = blockIdx.x * 128;
  mma_mainloop(A, BT, m0, n0, sA, sB, acc);
  const int tid = threadIdx.x, wid = tid >> 6, lane = tid & 63;
  const int wm = (wid >> 1) * 64, wn = (wid & 1) * 64, quad = lane >> 4, fm = lane & 15;
  #pragma unroll
  for (int i = 0; i < 4; ++i)
    #pragma unroll
    for (int r = 0; r < 4; ++r){
      size_t row = m0 + wm + i * 16 + quad * 4 + r;
      #pragma unroll
      for (int j = 0; j < 4; ++j){
        int col = n0 + wn + j * 16 + fm;
        C[row * 1024 + col] = f2bf(acc[i][j][r]);
      }
    }
}

// M[b] = SGbf[b] (32x1024) @ imgbf[b]^T (36x1024, padded to 48), fp32 out
__global__ __launch_bounds__(256) void batched_m_mfma(const ushort* __restrict__ SGbf,
                                                      const ushort* __restrict__ imgbf,
                                                      float* __restrict__ Mout){
  const int b = blockIdx.x;
  const int tid = threadIdx.x, wid = tid >> 6, lane = tid & 63;
  const int quad = lane >> 4, fm = lane & 15;
  __shared__ float red[4][32][48];
  f32x4 acc[2][3] = {};
  const int wk = wid * 256;              // K-quarter base
  const ushort* Ab = SGbf + (size_t)b * 32 * 1024;
  const ushort* Bb = imgbf + (size_t)b * 36 * 1024;
  #pragma unroll
  for (int ks = 0; ks < 8; ++ks){
    const int k = wk + ks * 32 + quad * 8;
    bf16x8 af[2], bg[3];
    af[0] = *(const bf16x8*)&Ab[(0*16 + fm) * 1024 + k];
    af[1] = *(const bf16x8*)&Ab[(1*16 + fm) * 1024 + k];
    bg[0] = *(const bf16x8*)&Bb[(0*16 + fm) * 1024 + k];
    bg[1] = *(const bf16x8*)&Bb[(1*16 + fm) * 1024 + k];
    bg[2] = *(const bf16x8*)&Bb[(2*16 + fm) * 1024 + k];  // rows 32..47: 36..47 are slack
    #pragma unroll
    for (int i = 0; i < 2; ++i)
      #pragma unroll
      for (int j = 0; j < 3; ++j)
        acc[i][j] = __builtin_amdgcn_mfma_f32_16x16x32_bf16(af[i], bg[j], acc[i][j], 0, 0, 0);
  }
  #pragma unroll
  for (int i = 0; i < 2; ++i)
    #pragma unroll
    for (int j = 0; j < 3; ++j)
      #pragma unroll
      for (int r = 0; r < 4; ++r)
        red[wid][i*16 + quad*4 + r][j*16 + fm] = acc[i][j][r];
  __syncthreads();
  #pragma unroll
  for (int q = 0; q < 5; ++q){
    int out = tid + 256 * q;
    if (out < N_*L_){
      int n = out / L_, l = out - n * L_;
      Mout[b * (N_*L_) + out] = red[0][n][l] + red[1][n][l] + red[2][n][l] + red[3][n][l];
    }
  }
}

// h1 = relu(Z@W1c + U[b,i] + V[b,j] + b1), bf16 out (63488 x 512)
__global__ __launch_bounds__(256) void gemm_z(const ushort* __restrict__ A,
                                              const ushort* __restrict__ BT,
                                              const ushort* __restrict__ UV,
                                              const float* __restrict__ b1,
                                              const int* __restrict__ iu, const int* __restrict__ ju,
                                              ushort* __restrict__ h1){
  __shared__ ushort sA[4096], sB[4096];
  f32x4 acc[4][4] = {};
  size_t m0 = (size_t)blockIdx.y * 128; int n0 = blockIdx.x * 128;
  mma_mainloop(A, BT, m0, n0, sA, sB, acc);
  const int tid = threadIdx.x, wid = tid >> 6, lane = tid & 63;
  const int wm = (wid >> 1) * 64, wn = (wid & 1) * 64, quad = lane >> 4, fm = lane & 15;
  #pragma unroll
  for (int i = 0; i < 4; ++i)
    #pragma unroll
    for (int r = 0; r < 4; ++r){
      int row = (int)m0 + wm + i * 16 + quad * 4 + r;
      int b = row / P_, p = row - b * P_;
      const ushort* Ur = UV + (size_t)(b * N_ + iu[p]) * 1024;
      const ushort* Vr = UV + (size_t)(b * N_ + ju[p]) * 1024 + 512;
      #pragma unroll
      for (int j = 0; j < 4; ++j){
        int col = n0 + wn + j * 16 + fm;
        float h = acc[i][j][r] + bf2f(Ur[col]) + bf2f(Vr[col]) + b1[col];
        h1[(size_t)row * 512 + col] = f2bf(fmaxf(h, 0.f));
      }
    }
}

// text += sum_col relu(h1@W2 + b2) * W3
__global__ __launch_bounds__(256) void gemm_h2(const ushort* __restrict__ A,
                                               const ushort* __restrict__ BT,
                                               const float* __restrict__ b2,
                                               const float* __restrict__ W3,
                                               float* __restrict__ text){
  __shared__ ushort sA[4096], sB[4096];
  f32x4 acc[4][4] = {};
  size_t m0 = (size_t)blockIdx.y * 128; int n0 = blockIdx.x * 128;
  mma_mainloop(A, BT, m0, n0, sA, sB, acc);
  const int tid = threadIdx.x, wid = tid >> 6, lane = tid & 63;
  const int wm = (wid >> 1) * 64, wn = (wid & 1) * 64, quad = lane >> 4, fm = lane & 15;
  #pragma unroll
  for (int i = 0; i < 4; ++i)
    #pragma unroll
    for (int r = 0; r < 4; ++r){
      int row = (int)m0 + wm + i * 16 + quad * 4 + r;
      float s = 0.f;
      #pragma unroll
      for (int j = 0; j < 4; ++j){
        int col = n0 + wn + j * 16 + fm;
        float h = fmaxf(acc[i][j][r] + b2[col], 0.f);
        s = fmaf(h, W3[col], s);
      }
      s += __shfl_xor(s, 1); s += __shfl_xor(s, 2); s += __shfl_xor(s, 4); s += __shfl_xor(s, 8);
      if (fm == 0) atomicAdd(&text[row], s);
    }
}

// ---------- small fp32 reduction kernels ----------
__global__ void msum_kernel(const float* __restrict__ M, const float* __restrict__ sm,
                            float* Msum, float* Mtot){
  const int i = blockIdx.x, t = threadIdx.x;  // 64 threads
  if (t < L_){
    float s = 0.f;
    for (int n = 0; n < N_; ++n) s += M[i*N_*L_ + n*L_ + t] * sm[i*N_ + n];
    Msum[i*L_ + t] = s;
  }
  float tot = 0.f;
  for (int idx = t; idx < N_*L_; idx += 64) tot += M[i*N_*L_ + idx];
  tot = wave_sum(tot);
  if (t == 0) Mtot[i] = tot;
}

__global__ void sent_kernel(const float* __restrict__ Msum, const float* __restrict__ im,
                            const float* __restrict__ cnt_s, const float* __restrict__ cnt_i,
                            const float* __restrict__ Mtot, float* __restrict__ sent){
  const int i = blockIdx.x, j = threadIdx.x;  // 128 threads
  float s = 0.f;
  for (int l = 0; l < L_; ++l) s += Msum[i*L_ + l] * im[j*L_ + l];
  const float d = cnt_s[i] * cnt_i[j];
  sent[i*B_ + j] = (d != 0.f) ? (s / d) : (Mtot[i] * (1.f/(float)(N_*L_)));
}

__global__ void lse_kernel(const float* __restrict__ sent, float* lse_r, float* lse_c, float* rsum){
  const int i = blockIdx.x, t = threadIdx.x;  // 128 threads = 2 waves
  const int wid = t >> 6, lane = t & 63;
  __shared__ float sh[2];
  const float vr = sent[i*B_ + t];
  const float vc = sent[t*B_ + i];

  float m = wave_max(vr);
  if (lane == 0) sh[wid] = m;
  __syncthreads();
  const float mr = fmaxf(sh[0], sh[1]);
  __syncthreads();
  float e = wave_sum(expf(vr - mr));
  if (lane == 0) sh[wid] = e;
  __syncthreads();
  const float ser = sh[0] + sh[1];
  __syncthreads();
  float rs = wave_sum(vr);
  if (lane == 0) sh[wid] = rs;
  __syncthreads();
  const float rst = sh[0] + sh[1];
  __syncthreads();
  float mc0 = wave_max(vc);
  if (lane == 0) sh[wid] = mc0;
  __syncthreads();
  const float mc = fmaxf(sh[0], sh[1]);
  __syncthreads();
  float ec = wave_sum(expf(vc - mc));
  if (lane == 0) sh[wid] = ec;
  __syncthreads();
  const float sec = sh[0] + sh[1];
  if (t == 0){
    lse_r[i] = mr + logf(ser);
    lse_c[i] = mc + logf(sec);
    rsum[i]  = rst;
  }
}

__global__ void loss_final(const float* __restrict__ lse_r, const float* __restrict__ lse_c,
                           const float* __restrict__ rsum, float* __restrict__ out){
  const int t = threadIdx.x;  // 128
  const int wid = t >> 6, lane = t & 63;
  __shared__ float sh[4];
  float a = lse_r[t] + lse_c[t];
  float c = rsum[t];
  float as = wave_sum(a);
  float cs = wave_sum(c);
  if (lane == 0){ sh[wid] = as; sh[2 + wid] = cs; }
  __syncthreads();
  if (t == 0){
    float A = sh[0] + sh[1], C = sh[2] + sh[3];
    out[0] = A - 2.f * C / (float)B_;
  }
}

__global__ void text_init(float* __restrict__ text, const float* __restrict__ b3){
  int r = blockIdx.x * 256 + threadIdx.x;
  if (r < R_) text[r] = b3[0];
}

extern "C" void kernel_launch(void* const* d_in, const int* in_sizes, int n_in,
                              void* d_out, int out_size, void* d_ws, size_t ws_size,
                              hipStream_t stream) {
  const float* span = (const float*)d_in[0];
  const float* img  = (const float*)d_in[1];
  const float* sm   = (const float*)d_in[2];
  const float* im   = (const float*)d_in[3];
  const float* Wg   = (const float*)d_in[4];
  const float* W1   = (const float*)d_in[5];
  const float* b1   = (const float*)d_in[6];
  const float* W2   = (const float*)d_in[7];
  const float* b2   = (const float*)d_in[8];
  const float* W3   = (const float*)d_in[9];
  const float* b3   = (const float*)d_in[10];

  float* out  = (float*)d_out;
  float* loss = out;
  float* Mout = out + 1;
  float* text = out + 1 + B_*N_*L_;

  ushort* wsu  = (ushort*)d_ws;
  ushort* h1bf = wsu;                          // R_*512
  ushort* Zbf  = h1bf + (size_t)R_*512;        // R_*512
  ushort* UVbf = Zbf + (size_t)R_*512;         // 4096*1024
  ushort* SGbf = UVbf + 4096*1024;             // 4096*1024
  ushort* spbf = SGbf + 4096*1024;             // 4096*512
  ushort* imgbf= spbf + 4096*512;              // 128*36*1024 + 12*1024 slack
  ushort* UVBT = imgbf + (size_t)(B_*L_ + 12)*1024; // 1024*512
  ushort* W1cT = UVBT + 1024*512;              // 512*512
  ushort* W2T  = W1cT + 512*512;               // 512*512
  ushort* WgT  = W2T + 512*512;                // 1024*512
  float* Msum  = (float*)(WgT + 1024*512);     // 4608
  float* Mtot  = Msum + B_*L_;
  float* cnt_s = Mtot + B_;
  float* cnt_i = cnt_s + B_;
  float* sent  = cnt_i + B_;                   // 16384
  float* lse_r = sent + B_*B_;
  float* lse_c = lse_r + B_;
  float* rsum  = lse_c + B_;
  int*   iu    = (int*)(rsum + B_);            // 496
  int*   ju    = iu + P_;                      // 496

  init_pairs<<<1, 512, 0, stream>>>(iu, ju);
  count_kernel<<<1, 256, 0, stream>>>(sm, im, cnt_s, cnt_i);

  // bf16 prep
  conv_f2bf<<<2048, 256, 0, stream>>>(span, spbf);                 // 4096*512
  conv_f2bf<<<4608, 256, 0, stream>>>(img, imgbf);                 // 128*36*1024
  transpose_bf<<<dim3(32,16), dim3(32,8), 0, stream>>>(Wg, WgT, 512, 1024);
  transpose_bf<<<dim3(16,16), dim3(32,8), 0, stream>>>(W1,            UVBT,            512, 512);
  transpose_bf<<<dim3(16,16), dim3(32,8), 0, stream>>>(W1 + 512*512,  UVBT + 512*512,  512, 512);
  transpose_bf<<<dim3(16,16), dim3(32,8), 0, stream>>>(W1 + 1024*512, W1cT,            512, 512);
  transpose_bf<<<dim3(16,16), dim3(32,8), 0, stream>>>(W2,            W2T,             512, 512);
  make_z<<<R_*512/4/256, 256, 0, stream>>>(span, iu, ju, Zbf);

  // M path (bf16 MFMA)
  gemm_sgbf<<<dim3(8, 32), 256, 0, stream>>>(spbf, WgT, SGbf);
  batched_m_mfma<<<B_, 256, 0, stream>>>(SGbf, imgbf, Mout);
  msum_kernel<<<B_, 64, 0, stream>>>(Mout, sm, Msum, Mtot);
  sent_kernel<<<B_, B_, 0, stream>>>(Msum, im, cnt_s, cnt_i, Mtot, sent);
  lse_kernel<<<B_, B_, 0, stream>>>(sent, lse_r, lse_c, rsum);
  loss_final<<<1, B_, 0, stream>>>(lse_r, lse_c, rsum, loss);

  // text path (bf16 MFMA)
  gemm_uv<<<dim3(8, 32),  256, 0, stream>>>(spbf, UVBT, UVbf);
  gemm_z <<<dim3(4, 496), 256, 0, stream>>>(Zbf, W1cT, UVbf, b1, iu, ju, h1bf);
  text_init<<<R_/256, 256, 0, stream>>>(text, b3);
  gemm_h2<<<dim3(4, 496), 256, 0, stream>>>(h1bf, W2T, b2, W3, text);
}